// Round 5
// baseline (920.497 us; speedup 1.0000x reference)
//
#include <hip/hip_runtime.h>
#include <math.h>

#define N_IMG 128
#define EPS 1e-5f
#define PART_STRIDE 1614848   // float stride between qb/kb/vb/midb partial buffers
#define OP_STRIDE 1613824     // o_part per-slice stride (128*4*197*16)
#define LP_STRIDE 100864      // l_part per-slice stride (128*4*197)

// ---------- helpers ----------
__device__ __forceinline__ float gelu_f(float x) {
    return 0.5f * x * (1.0f + erff(x * 0.70710678118654752f));
}

__device__ __forceinline__ float wave_sum(float v) {
    #pragma unroll
    for (int m = 1; m < 64; m <<= 1) v += __shfl_xor(v, m);
    return v;
}

__device__ __forceinline__ void fma4(float4& acc, float s, const float4& v) {
    acc.x += s * v.x; acc.y += s * v.y; acc.z += s * v.z; acc.w += s * v.w;
}

__device__ __forceinline__ float dot4(const float4& a, const float4& b) {
    return a.x * b.x + a.y * b.y + a.z * b.z + a.w * b.w;
}

// ---------- positional-embedding table: pe[197][64] ----------
__global__ void k_posemb(float* __restrict__ pe) {
    int idx = blockIdx.x * 256 + threadIdx.x;
    if (idx >= 197 * 64) return;
    int i = idx >> 6, j = idx & 63;
    int jj = j & ~1;
    float inv = powf(10000.0f, (float)jj / 64.0f);
    float a = (float)i / inv;
    pe[idx] = (j & 1) ? cosf(a) : sinf(a);
}

// ---------- patch embed, split-K x4: part[y] = patchify(img) @ lm_W[k-range y] ----------
__global__ __launch_bounds__(256, 6) void k_patch(
    const float* __restrict__ img, const float* __restrict__ W,
    float* __restrict__ part)
{
    __shared__ float As[64 * 44];
    __shared__ float Bs[32 * 76];
    int tid = threadIdx.x;
    int tx = tid & 15, ty = tid >> 4;
    int m0 = blockIdx.x * 64;
    int kc0 = blockIdx.y * 8;

    int ra = tid >> 2, ca = (tid & 3) * 8;
    int rowa = m0 + ra;
    int na = rowa / 196, pa = rowa - na * 196;
    const float* abase = img + (size_t)na * 200704 + (pa / 14) * (32 * 448) + (pa % 14) * 32 + ca;

    int kr = tid >> 3, cb = (tid & 7) * 8;

    float4 acc[4];
    #pragma unroll
    for (int i = 0; i < 4; ++i) acc[i] = make_float4(0.f, 0.f, 0.f, 0.f);

    for (int it = 0; it < 8; ++it) {
        int kc = kc0 + it;
        float4 a0 = *(const float4*)(abase + kc * 448);
        float4 a1 = *(const float4*)(abase + kc * 448 + 4);
        const float* wp = W + (size_t)(kc * 32 + kr) * 64 + cb;
        float4 b0 = *(const float4*)(wp);
        float4 b1 = *(const float4*)(wp + 4);
        __syncthreads();
        *(float4*)&As[ra * 44 + ca]     = a0;
        *(float4*)&As[ra * 44 + ca + 4] = a1;
        *(float4*)&Bs[kr * 76 + cb]     = b0;
        *(float4*)&Bs[kr * 76 + cb + 4] = b1;
        __syncthreads();
        #pragma unroll 4
        for (int k4 = 0; k4 < 8; ++k4) {
            float4 a[4], b[4];
            #pragma unroll
            for (int i = 0; i < 4; ++i) a[i] = *(float4*)&As[(ty + 16 * i) * 44 + k4 * 4];
            #pragma unroll
            for (int kk = 0; kk < 4; ++kk) b[kk] = *(float4*)&Bs[(k4 * 4 + kk) * 76 + tx * 4];
            #pragma unroll
            for (int i = 0; i < 4; ++i) {
                fma4(acc[i], a[i].x, b[0]);
                fma4(acc[i], a[i].y, b[1]);
                fma4(acc[i], a[i].z, b[2]);
                fma4(acc[i], a[i].w, b[3]);
            }
        }
    }
    float* pp = part + (size_t)blockIdx.y * PART_STRIDE;
    int col = tx * 4;
    #pragma unroll
    for (int i = 0; i < 4; ++i) {
        int row = m0 + ty + 16 * i;
        *(float4*)&pp[(size_t)row * 64 + col] = acc[i];
    }
}

// ---------- combine split-K partials + bias + pos-emb -> x ----------
__global__ __launch_bounds__(256) void k_pcomb(
    const float* __restrict__ part, const float* __restrict__ bias,
    const float* __restrict__ pe, float* __restrict__ x)
{
    int idx = blockIdx.x * 256 + threadIdx.x;      // 0 .. 25088*16-1
    int row = idx >> 4, c4 = (idx & 15) * 4;
    int n = row / 196, p = row - n * 196;
    const float* p0 = part + (size_t)row * 64 + c4;
    float4 a = *(const float4*)(p0);
    float4 b = *(const float4*)(p0 + PART_STRIDE);
    float4 c = *(const float4*)(p0 + 2 * (size_t)PART_STRIDE);
    float4 d = *(const float4*)(p0 + 3 * (size_t)PART_STRIDE);
    float4 bb = *(const float4*)(bias + c4);
    float4 pv = *(const float4*)(pe + (size_t)(1 + p) * 64 + c4);
    float4 o;
    o.x = a.x + b.x + c.x + d.x + bb.x + pv.x;
    o.y = a.y + b.y + c.y + d.y + bb.y + pv.y;
    o.z = a.z + b.z + c.z + d.z + bb.z + pv.z;
    o.w = a.w + b.w + c.w + d.w + bb.w + pv.w;
    *(float4*)&x[((size_t)(n * 197 + 1 + p)) * 64 + c4] = o;
}

// ---------- class-token row ----------
__global__ void k_cls(const float* __restrict__ cls, const float* __restrict__ pe,
                      float* __restrict__ x) {
    int idx = blockIdx.x * 256 + threadIdx.x;
    if (idx >= 128 * 64) return;
    int n = idx >> 6, j = idx & 63;
    x[(size_t)n * 197 * 64 + j] = cls[j] + pe[j];
}

// ---------- LN1 + QKV projection ----------
__global__ __launch_bounds__(256, 2) void k_ln_qkv(
    const float* __restrict__ x, const float* __restrict__ g, const float* __restrict__ bta,
    const float* __restrict__ Wq, const float* __restrict__ bq,
    const float* __restrict__ Wk, const float* __restrict__ bk,
    const float* __restrict__ Wv, const float* __restrict__ bv,
    float* __restrict__ q, float* __restrict__ k, float* __restrict__ v, int S)
{
    __shared__ float z[4][64];
    int tid = threadIdx.x, w = tid >> 6, l = tid & 63;
    int row = blockIdx.x * 4 + w;
    if (row >= N_IMG * S) return;
    float xv = x[(size_t)row * 64 + l];
    float m = wave_sum(xv) * (1.0f / 64.0f);
    float t = xv - m;
    float var = wave_sum(t * t) * (1.0f / 64.0f);
    float zv = t * rsqrtf(var + EPS) * g[l] + bta[l];
    z[w][l] = zv;
    int h = l >> 4, e = l & 15;
    const float* zh = &z[w][h * 16];
    const float* wq = Wq + h * 256 + e;
    const float* wk = Wk + h * 256 + e;
    const float* wv = Wv + h * 256 + e;
    float aq = bq[l], ak = bk[l], av = bv[l];
    #pragma unroll
    for (int d = 0; d < 16; ++d) {
        float zd = zh[d];
        aq += zd * wq[d * 16];
        ak += zd * wk[d * 16];
        av += zd * wv[d * 16];
    }
    int n = row / S, s = row - n * S;
    size_t o = ((size_t)((n * 4 + h) * S + s)) * 16 + e;
    q[o] = aq; k[o] = ak; v[o] = av;
}

// ---------- attention partials: flash-style split-K x4 over key slices ----------
struct KV { float4 k[2][4]; float4 v[2][4]; };

__device__ __forceinline__ void ld_pair(KV& b, const float* kp, const float* vp, int j) {
    #pragma unroll
    for (int u = 0; u < 2; ++u) {
        #pragma unroll
        for (int c = 0; c < 4; ++c) {
            b.k[u][c] = *(const float4*)(kp + (size_t)(j + u) * 16 + c * 4);
            b.v[u][c] = *(const float4*)(vp + (size_t)(j + u) * 16 + c * 4);
        }
    }
}

__device__ __forceinline__ void comp_one(const KV& b, int u, const float4* qv,
                                         float& l, float4* o) {
    float sc = dot4(qv[0], b.k[u][0]) + dot4(qv[1], b.k[u][1]) +
               dot4(qv[2], b.k[u][2]) + dot4(qv[3], b.k[u][3]);
    float p = __expf(sc);
    l += p;
    fma4(o[0], p, b.v[u][0]); fma4(o[1], p, b.v[u][1]);
    fma4(o[2], p, b.v[u][2]); fma4(o[3], p, b.v[u][3]);
}

// grid (512, 4): blockIdx.x = n*4+h, blockIdx.y = key slice (~50 keys).
__global__ __launch_bounds__(256, 8) void k_attn_part(
    const float* __restrict__ q, const float* __restrict__ k, const float* __restrict__ v,
    float* __restrict__ o_part, float* __restrict__ l_part, int S)
{
    int h = blockIdx.x & 3, n = blockIdx.x >> 2;
    int ks = blockIdx.y;
    int per = (S + 3) >> 2;
    int start = ks * per;
    int len = S - start; if (len > per) len = per;
    int tid = threadIdx.x;
    int s = tid < S ? tid : S - 1;
    const float* qrow = q + ((size_t)((n * 4 + h) * S + s)) * 16;
    float4 qv[4];
    #pragma unroll
    for (int c = 0; c < 4; ++c) {
        float4 t = *(const float4*)(qrow + c * 4);
        t.x *= 0.25f; t.y *= 0.25f; t.z *= 0.25f; t.w *= 0.25f;
        qv[c] = t;
    }
    const float* kp = k + ((size_t)(n * 4 + h) * S + start) * 16;
    const float* vp = v + ((size_t)(n * 4 + h) * S + start) * 16;
    float l = 0.0f;
    float4 o[4];
    #pragma unroll
    for (int c = 0; c < 4; ++c) o[c] = make_float4(0.f, 0.f, 0.f, 0.f);

    KV A, B;
    ld_pair(A, kp, vp, 0);
    int j = 0;
    for (; j + 4 <= len; j += 4) {
        ld_pair(B, kp, vp, j + 2);
        comp_one(A, 0, qv, l, o);
        comp_one(A, 1, qv, l, o);
        ld_pair(A, kp, vp, j + 4);
        comp_one(B, 0, qv, l, o);
        comp_one(B, 1, qv, l, o);
    }
    int rem = len - j;
    if (rem > 0) comp_one(A, 0, qv, l, o);
    if (rem > 1) comp_one(A, 1, qv, l, o);
    if (rem > 2) {
        ld_pair(B, kp, vp, j + 2);
        comp_one(B, 0, qv, l, o);
    }

    if (tid < S) {
        size_t qlin = (size_t)(n * 4 + h) * S + tid;
        float* op = o_part + (size_t)ks * OP_STRIDE + qlin * 16;
        #pragma unroll
        for (int c = 0; c < 4; ++c) *(float4*)(op + c * 4) = o[c];
        l_part[(size_t)ks * LP_STRIDE + qlin] = l;
    }
}

// ---------- fused attn-combine + LN2 + GEMM [rows,64]@[64,256] + bias + GELU -> mid ----------
// grid (rows/64, 4). Assembles h = x + (sum o_part)/(sum l_part) in registers (bit-identical
// to the old comb kernel), writes h to hout only from the nc==0 slice, LNs, GEMMs one 64-col tile.
__global__ __launch_bounds__(256, 4) void k_mlp1(
    const float* __restrict__ x, const float* __restrict__ o_part, const float* __restrict__ l_part,
    const float* __restrict__ g, const float* __restrict__ bta,
    const float* __restrict__ W1, const float* __restrict__ b1,
    float* __restrict__ hout, float* __restrict__ mid, int S)
{
    __shared__ float As[64 * 76];
    __shared__ float Bs[64 * 76];
    int tid = threadIdx.x;
    int tx = tid & 15, ty = tid >> 4;
    int m0 = blockIdx.x * 64;
    int nc = blockIdx.y;
    int r = tid >> 2, cpart = (tid & 3) * 16;
    {
        int row = m0 + r;
        int n = row / S, s = row - n * S;
        int h = cpart >> 4;
        size_t qlin = (size_t)((n * 4 + h) * S + s);
        float l = l_part[qlin] + l_part[qlin + LP_STRIDE] +
                  l_part[qlin + 2 * LP_STRIDE] + l_part[qlin + 3 * LP_STRIDE];
        float rl = 1.0f / l;
        const float* op = o_part + qlin * 16;
        const float* xp = x + (size_t)row * 64 + cpart;
        float4 hv[4];
        #pragma unroll
        for (int i = 0; i < 4; ++i) {
            float4 a = *(const float4*)(op + i * 4);
            float4 b = *(const float4*)(op + i * 4 + OP_STRIDE);
            float4 c = *(const float4*)(op + i * 4 + 2 * (size_t)OP_STRIDE);
            float4 d = *(const float4*)(op + i * 4 + 3 * (size_t)OP_STRIDE);
            float4 xv = *(const float4*)(xp + i * 4);
            hv[i].x = xv.x + (a.x + b.x + c.x + d.x) * rl;
            hv[i].y = xv.y + (a.y + b.y + c.y + d.y) * rl;
            hv[i].z = xv.z + (a.z + b.z + c.z + d.z) * rl;
            hv[i].w = xv.w + (a.w + b.w + c.w + d.w) * rl;
        }
        if (nc == 0) {
            float* hp = hout + (size_t)row * 64 + cpart;
            #pragma unroll
            for (int i = 0; i < 4; ++i) *(float4*)(hp + i * 4) = hv[i];
        }
        float ps = 0.f;
        #pragma unroll
        for (int i = 0; i < 4; ++i) ps += hv[i].x + hv[i].y + hv[i].z + hv[i].w;
        ps += __shfl_xor(ps, 1); ps += __shfl_xor(ps, 2);
        float mean = ps * (1.0f / 64.0f);
        float vs = 0.f;
        #pragma unroll
        for (int i = 0; i < 4; ++i) {
            float dx = hv[i].x - mean, dy = hv[i].y - mean, dz = hv[i].z - mean, dw = hv[i].w - mean;
            vs += dx * dx + dy * dy + dz * dz + dw * dw;
        }
        vs += __shfl_xor(vs, 1); vs += __shfl_xor(vs, 2);
        float rstd = rsqrtf(vs * (1.0f / 64.0f) + EPS);
        #pragma unroll
        for (int i = 0; i < 4; ++i) {
            float4 gv = *(const float4*)(g + cpart + i * 4);
            float4 bv = *(const float4*)(bta + cpart + i * 4);
            float4 zv;
            zv.x = (hv[i].x - mean) * rstd * gv.x + bv.x;
            zv.y = (hv[i].y - mean) * rstd * gv.y + bv.y;
            zv.z = (hv[i].z - mean) * rstd * gv.z + bv.z;
            zv.w = (hv[i].w - mean) * rstd * gv.w + bv.w;
            *(float4*)&As[r * 76 + cpart + i * 4] = zv;
        }
    }
    const float* wp = W1 + (size_t)r * 256 + nc * 64 + cpart;
    float4 wv4[4];
    #pragma unroll
    for (int i = 0; i < 4; ++i) wv4[i] = *(const float4*)(wp + i * 4);
    __syncthreads();
    #pragma unroll
    for (int i = 0; i < 4; ++i)
        *(float4*)&Bs[r * 76 + cpart + i * 4] = wv4[i];
    __syncthreads();
    float4 acc[4];
    #pragma unroll
    for (int i = 0; i < 4; ++i) acc[i] = make_float4(0.f, 0.f, 0.f, 0.f);
    #pragma unroll 4
    for (int k4 = 0; k4 < 16; ++k4) {
        float4 a[4], b[4];
        #pragma unroll
        for (int i = 0; i < 4; ++i) a[i] = *(float4*)&As[(ty + 16 * i) * 76 + k4 * 4];
        #pragma unroll
        for (int kk = 0; kk < 4; ++kk) b[kk] = *(float4*)&Bs[(k4 * 4 + kk) * 76 + tx * 4];
        #pragma unroll
        for (int i = 0; i < 4; ++i) {
            fma4(acc[i], a[i].x, b[0]);
            fma4(acc[i], a[i].y, b[1]);
            fma4(acc[i], a[i].z, b[2]);
            fma4(acc[i], a[i].w, b[3]);
        }
    }
    int col = nc * 64 + tx * 4;
    float4 b1v = *(const float4*)(b1 + col);
    #pragma unroll
    for (int i = 0; i < 4; ++i) {
        int row = m0 + ty + 16 * i;
        float4 ov;
        ov.x = gelu_f(acc[i].x + b1v.x);
        ov.y = gelu_f(acc[i].y + b1v.y);
        ov.z = gelu_f(acc[i].z + b1v.z);
        ov.w = gelu_f(acc[i].w + b1v.w);
        *(float4*)&mid[(size_t)row * 256 + col] = ov;
    }
}

// ---------- GEMM [rows,256]@[256,64] + bias + residual -> out ----------
__global__ __launch_bounds__(256, 4) void k_mlp2(
    const float* __restrict__ mid, const float* __restrict__ W2, const float* __restrict__ b2,
    const float* __restrict__ hbuf, float* __restrict__ out)
{
    __shared__ float As[32 * 76];
    __shared__ float Bs[64 * 76];
    int tid = threadIdx.x;
    int tx = tid & 15, ty = tid >> 4;
    int m0 = blockIdx.x * 32;
    int ra = tid >> 3, ca = (tid & 7) * 8;
    int rb = tid >> 2, cb = (tid & 3) * 16;
    float4 acc[2];
    acc[0] = make_float4(0.f, 0.f, 0.f, 0.f);
    acc[1] = make_float4(0.f, 0.f, 0.f, 0.f);
    for (int kc = 0; kc < 4; ++kc) {
        const float* mp = mid + ((size_t)(m0 + ra)) * 256 + kc * 64 + ca;
        float4 av0 = *(const float4*)(mp);
        float4 av1 = *(const float4*)(mp + 4);
        const float* wp = W2 + (size_t)(kc * 64 + rb) * 64 + cb;
        float4 wv4[4];
        #pragma unroll
        for (int i = 0; i < 4; ++i) wv4[i] = *(const float4*)(wp + i * 4);
        __syncthreads();
        *(float4*)&As[ra * 76 + ca]     = av0;
        *(float4*)&As[ra * 76 + ca + 4] = av1;
        #pragma unroll
        for (int i = 0; i < 4; ++i)
            *(float4*)&Bs[rb * 76 + cb + i * 4] = wv4[i];
        __syncthreads();
        #pragma unroll 4
        for (int k4 = 0; k4 < 16; ++k4) {
            float4 a[2], b[4];
            a[0] = *(float4*)&As[ty * 76 + k4 * 4];
            a[1] = *(float4*)&As[(ty + 16) * 76 + k4 * 4];
            #pragma unroll
            for (int kk = 0; kk < 4; ++kk) b[kk] = *(float4*)&Bs[(k4 * 4 + kk) * 76 + tx * 4];
            #pragma unroll
            for (int i = 0; i < 2; ++i) {
                fma4(acc[i], a[i].x, b[0]);
                fma4(acc[i], a[i].y, b[1]);
                fma4(acc[i], a[i].z, b[2]);
                fma4(acc[i], a[i].w, b[3]);
            }
        }
    }
    int col = tx * 4;
    float4 b2v = *(const float4*)(b2 + col);
    #pragma unroll
    for (int i = 0; i < 2; ++i) {
        int row = m0 + ty + 16 * i;
        float4 hv = *(const float4*)(hbuf + (size_t)row * 64 + col);
        float4 ov;
        ov.x = acc[i].x + b2v.x + hv.x;
        ov.y = acc[i].y + b2v.y + hv.y;
        ov.z = acc[i].z + b2v.z + hv.z;
        ov.w = acc[i].w + b2v.w + hv.w;
        *(float4*)&out[(size_t)row * 64 + col] = ov;
    }
}

// ---------- bottleneck ----------
__global__ __launch_bounds__(256) void k_bneck(
    const float* __restrict__ xenc, const float* __restrict__ m1W, const float* __restrict__ m1b,
    const float* __restrict__ m4W, const float* __restrict__ m4b,
    float* __restrict__ lat_out, float* __restrict__ xdec)
{
    int tid = threadIdx.x, w = tid >> 6, l = tid & 63;
    int row = blockIdx.x * 4 + w;
    if (row >= 128 * 196) return;
    int n = row / 196, p = row - n * 196;
    float xv = xenc[((size_t)(n * 197 + 1 + p)) * 64 + l];
    float sum = wave_sum(xv * m1W[l]);
    float lat = gelu_f(sum + m1b[0]);
    if (l == 0) lat_out[row] = lat;
    float ov = gelu_f(lat * m4W[l] + m4b[l]);
    xdec[(size_t)row * 64 + l] = ov;
}

// ---------- final: img = depatchify((x + pe196) @ lm2_W + lm2_b) ----------
// BM=32, grid (784, 8), 2 col-tiles per block: 6272 blocks (~24.5/CU), LDS 29 KB (5 blocks/CU).
__global__ __launch_bounds__(256, 4) void k_final(
    const float* __restrict__ xdec, const float* __restrict__ pe,
    const float* __restrict__ W, const float* __restrict__ bias,
    float* __restrict__ img_out)
{
    __shared__ float As[32 * 76];
    __shared__ float Bs[64 * 76];
    int tid = threadIdx.x;
    int tx = tid & 15, ty = tid >> 4;
    int m0 = blockIdx.x * 32;
    int ra = tid >> 3, ca = (tid & 7) * 8;
    int rb = tid >> 2, cb = (tid & 3) * 16;
    {
        int row = m0 + ra;
        int n = row / 196, p = row - n * 196;
        const float* xp = xdec + (size_t)row * 64 + ca;
        const float* pp = pe + (size_t)p * 64 + ca;
        #pragma unroll
        for (int i = 0; i < 2; ++i) {
            float4 xv = *(const float4*)(xp + i * 4);
            float4 pv = *(const float4*)(pp + i * 4);
            float4 zv;
            zv.x = xv.x + pv.x; zv.y = xv.y + pv.y; zv.z = xv.z + pv.z; zv.w = xv.w + pv.w;
            *(float4*)&As[ra * 76 + ca + i * 4] = zv;
        }
    }
    for (int t = 0; t < 2; ++t) {
        int nb = blockIdx.y * 2 + t;
        const float* wp = W + (size_t)rb * 1024 + nb * 64 + cb;
        float4 wv4[4];
        #pragma unroll
        for (int i = 0; i < 4; ++i) wv4[i] = *(const float4*)(wp + i * 4);
        __syncthreads();
        #pragma unroll
        for (int i = 0; i < 4; ++i)
            *(float4*)&Bs[rb * 76 + cb + i * 4] = wv4[i];
        __syncthreads();
        float4 acc[2];
        acc[0] = make_float4(0.f, 0.f, 0.f, 0.f);
        acc[1] = make_float4(0.f, 0.f, 0.f, 0.f);
        #pragma unroll 4
        for (int k4 = 0; k4 < 16; ++k4) {
            float4 a[2], b[4];
            a[0] = *(float4*)&As[ty * 76 + k4 * 4];
            a[1] = *(float4*)&As[(ty + 16) * 76 + k4 * 4];
            #pragma unroll
            for (int kk = 0; kk < 4; ++kk) b[kk] = *(float4*)&Bs[(k4 * 4 + kk) * 76 + tx * 4];
            #pragma unroll
            for (int i = 0; i < 2; ++i) {
                fma4(acc[i], a[i].x, b[0]);
                fma4(acc[i], a[i].y, b[1]);
                fma4(acc[i], a[i].z, b[2]);
                fma4(acc[i], a[i].w, b[3]);
            }
        }
        int colj = nb * 64 + tx * 4;
        float4 bv = *(const float4*)(bias + colj);
        int rr = colj >> 5, cc = colj & 31;
        #pragma unroll
        for (int i = 0; i < 2; ++i) {
            int row = m0 + ty + 16 * i;
            int n = row / 196, p = row - n * 196;
            int pi = p / 14, pj = p - pi * 14;
            size_t off = (size_t)n * 200704 + (size_t)(pi * 32 + rr) * 448 + pj * 32 + cc;
            float4 ov;
            ov.x = acc[i].x + bv.x;
            ov.y = acc[i].y + bv.y;
            ov.z = acc[i].z + bv.z;
            ov.w = acc[i].w + bv.w;
            *(float4*)&img_out[off] = ov;
        }
    }
}

// ---------- host launch ----------
extern "C" void kernel_launch(void* const* d_in, const int* in_sizes, int n_in,
                              void* d_out, int out_size, void* d_ws, size_t ws_size,
                              hipStream_t stream) {
    const float* images = (const float*)d_in[0];
    const float* cls    = (const float*)d_in[1];
    const float* lm_W   = (const float*)d_in[2];
    const float* lm_b   = (const float*)d_in[3];
    const float* lm2_W  = (const float*)d_in[4];
    const float* lm2_b  = (const float*)d_in[5];
    const float* m1W    = (const float*)d_in[6];
    const float* m1b    = (const float*)d_in[7];
    const float* m4W    = (const float*)d_in[8];
    const float* m4b    = (const float*)d_in[9];

    float* pe   = (float*)d_ws;
    float* xb   = pe + 12608;          // 128*197*64
    float* hb   = xb + 1614848;
    float* qb   = hb + 1614848;        // qb/kb/vb/midb: contiguous, stride PART_STRIDE
    float* kb   = qb + 1614848;
    float* vb   = kb + 1614848;
    float* midb = vb + 1614848;        // 25216*256

    float* lat_out = (float*)d_out;            // 128*196 floats
    float* img_out = (float*)d_out + 25088;    // 128*448*448 floats; doubles as o_part/l_part scratch
    float* o_part  = img_out;                  // 4 * OP_STRIDE floats
    float* l_part  = img_out + 4 * (size_t)OP_STRIDE;  // 4 * LP_STRIDE floats

    hipLaunchKernelGGL(k_posemb, dim3(50), dim3(256), 0, stream, pe);
    hipLaunchKernelGGL(k_patch, dim3(392, 4), dim3(256), 0, stream, images, lm_W, qb);
    hipLaunchKernelGGL(k_pcomb, dim3(1568), dim3(256), 0, stream, qb, lm_b, pe, xb);
    hipLaunchKernelGGL(k_cls, dim3(32), dim3(256), 0, stream, cls, pe, xb);

    float* cur_x = xb;
    float* cur_h = hb;
    for (int grp = 0; grp < 2; ++grp) {
        int base = 10 + grp * 14;
        const float* ln1_g = (const float*)d_in[base + 0];
        const float* ln1_b = (const float*)d_in[base + 1];
        const float* ln2_g = (const float*)d_in[base + 2];
        const float* ln2_b = (const float*)d_in[base + 3];
        const float* Wq = (const float*)d_in[base + 4];
        const float* Wk = (const float*)d_in[base + 5];
        const float* Wv = (const float*)d_in[base + 6];
        const float* bq = (const float*)d_in[base + 7];
        const float* bk = (const float*)d_in[base + 8];
        const float* bv = (const float*)d_in[base + 9];
        const float* W1 = (const float*)d_in[base + 10];
        const float* b1 = (const float*)d_in[base + 11];
        const float* W2 = (const float*)d_in[base + 12];
        const float* b2 = (const float*)d_in[base + 13];
        int S = (grp == 0) ? 197 : 196;
        int rows = 128 * S;
        for (int i = 0; i < 2; ++i) {
            hipLaunchKernelGGL(k_ln_qkv, dim3(rows / 4), dim3(256), 0, stream,
                cur_x, ln1_g + i * 64, ln1_b + i * 64,
                Wq + i * 1024, bq + i * 64, Wk + i * 1024, bk + i * 64,
                Wv + i * 1024, bv + i * 64, qb, kb, vb, S);
            hipLaunchKernelGGL(k_attn_part, dim3(512, 4), dim3(256), 0, stream,
                qb, kb, vb, o_part, l_part, S);
            // fused: combine partials + residual + LN2 + GEMM1
            hipLaunchKernelGGL(k_mlp1, dim3(rows / 64, 4), dim3(256), 0, stream,
                cur_x, o_part, l_part, ln2_g + i * 64, ln2_b + i * 64,
                W1 + i * 16384, b1 + i * 256, cur_h, midb, S);
            hipLaunchKernelGGL(k_mlp2, dim3(rows / 32), dim3(256), 0, stream,
                midb, W2 + i * 16384, b2 + i * 64, cur_h, cur_x);
        }
        if (grp == 0) {
            hipLaunchKernelGGL(k_bneck, dim3(6272), dim3(256), 0, stream,
                cur_x, m1W, m1b, m4W, m4b, lat_out, hb);
            cur_x = hb;
            cur_h = xb;
        }
    }
    hipLaunchKernelGGL(k_final, dim3(784, 8), dim3(256), 0, stream, cur_x, pe, lm2_W, lm2_b, img_out);
}

// Round 6
// 818.982 us; speedup vs baseline: 1.1240x; 1.1240x over previous
//
#include <hip/hip_runtime.h>
#include <math.h>

#define N_IMG 128
#define EPS 1e-5f
#define PART_STRIDE 1614848   // float stride between qb/kb/vb/midb partial buffers
#define OP_STRIDE 1613824     // o_part per-slice stride (128*4*197*16)
#define LP_STRIDE 100864      // l_part per-slice stride (128*4*197)

// ---------- helpers ----------
__device__ __forceinline__ float gelu_f(float x) {
    return 0.5f * x * (1.0f + erff(x * 0.70710678118654752f));
}

__device__ __forceinline__ float wave_sum(float v) {
    #pragma unroll
    for (int m = 1; m < 64; m <<= 1) v += __shfl_xor(v, m);
    return v;
}

__device__ __forceinline__ void fma4(float4& acc, float s, const float4& v) {
    acc.x += s * v.x; acc.y += s * v.y; acc.z += s * v.z; acc.w += s * v.w;
}

__device__ __forceinline__ float dot4(const float4& a, const float4& b) {
    return a.x * b.x + a.y * b.y + a.z * b.z + a.w * b.w;
}

// ---------- positional-embedding table: pe[197][64] ----------
__global__ void k_posemb(float* __restrict__ pe) {
    int idx = blockIdx.x * 256 + threadIdx.x;
    if (idx >= 197 * 64) return;
    int i = idx >> 6, j = idx & 63;
    int jj = j & ~1;
    float inv = powf(10000.0f, (float)jj / 64.0f);
    float a = (float)i / inv;
    pe[idx] = (j & 1) ? cosf(a) : sinf(a);
}

// ---------- patch embed, split-K x4: part[y] = patchify(img) @ lm_W[k-range y] ----------
__global__ __launch_bounds__(256, 6) void k_patch(
    const float* __restrict__ img, const float* __restrict__ W,
    float* __restrict__ part)
{
    __shared__ float As[64 * 44];
    __shared__ float Bs[32 * 76];
    int tid = threadIdx.x;
    int tx = tid & 15, ty = tid >> 4;
    int m0 = blockIdx.x * 64;
    int kc0 = blockIdx.y * 8;

    int ra = tid >> 2, ca = (tid & 3) * 8;
    int rowa = m0 + ra;
    int na = rowa / 196, pa = rowa - na * 196;
    const float* abase = img + (size_t)na * 200704 + (pa / 14) * (32 * 448) + (pa % 14) * 32 + ca;

    int kr = tid >> 3, cb = (tid & 7) * 8;

    float4 acc[4];
    #pragma unroll
    for (int i = 0; i < 4; ++i) acc[i] = make_float4(0.f, 0.f, 0.f, 0.f);

    for (int it = 0; it < 8; ++it) {
        int kc = kc0 + it;
        float4 a0 = *(const float4*)(abase + kc * 448);
        float4 a1 = *(const float4*)(abase + kc * 448 + 4);
        const float* wp = W + (size_t)(kc * 32 + kr) * 64 + cb;
        float4 b0 = *(const float4*)(wp);
        float4 b1 = *(const float4*)(wp + 4);
        __syncthreads();
        *(float4*)&As[ra * 44 + ca]     = a0;
        *(float4*)&As[ra * 44 + ca + 4] = a1;
        *(float4*)&Bs[kr * 76 + cb]     = b0;
        *(float4*)&Bs[kr * 76 + cb + 4] = b1;
        __syncthreads();
        #pragma unroll 4
        for (int k4 = 0; k4 < 8; ++k4) {
            float4 a[4], b[4];
            #pragma unroll
            for (int i = 0; i < 4; ++i) a[i] = *(float4*)&As[(ty + 16 * i) * 44 + k4 * 4];
            #pragma unroll
            for (int kk = 0; kk < 4; ++kk) b[kk] = *(float4*)&Bs[(k4 * 4 + kk) * 76 + tx * 4];
            #pragma unroll
            for (int i = 0; i < 4; ++i) {
                fma4(acc[i], a[i].x, b[0]);
                fma4(acc[i], a[i].y, b[1]);
                fma4(acc[i], a[i].z, b[2]);
                fma4(acc[i], a[i].w, b[3]);
            }
        }
    }
    float* pp = part + (size_t)blockIdx.y * PART_STRIDE;
    int col = tx * 4;
    #pragma unroll
    for (int i = 0; i < 4; ++i) {
        int row = m0 + ty + 16 * i;
        *(float4*)&pp[(size_t)row * 64 + col] = acc[i];
    }
}

// ---------- combine split-K partials + bias + pos-emb -> x ----------
__global__ __launch_bounds__(256) void k_pcomb(
    const float* __restrict__ part, const float* __restrict__ bias,
    const float* __restrict__ pe, float* __restrict__ x)
{
    int idx = blockIdx.x * 256 + threadIdx.x;      // 0 .. 25088*16-1
    int row = idx >> 4, c4 = (idx & 15) * 4;
    int n = row / 196, p = row - n * 196;
    const float* p0 = part + (size_t)row * 64 + c4;
    float4 a = *(const float4*)(p0);
    float4 b = *(const float4*)(p0 + PART_STRIDE);
    float4 c = *(const float4*)(p0 + 2 * (size_t)PART_STRIDE);
    float4 d = *(const float4*)(p0 + 3 * (size_t)PART_STRIDE);
    float4 bb = *(const float4*)(bias + c4);
    float4 pv = *(const float4*)(pe + (size_t)(1 + p) * 64 + c4);
    float4 o;
    o.x = a.x + b.x + c.x + d.x + bb.x + pv.x;
    o.y = a.y + b.y + c.y + d.y + bb.y + pv.y;
    o.z = a.z + b.z + c.z + d.z + bb.z + pv.z;
    o.w = a.w + b.w + c.w + d.w + bb.w + pv.w;
    *(float4*)&x[((size_t)(n * 197 + 1 + p)) * 64 + c4] = o;
}

// ---------- class-token row ----------
__global__ void k_cls(const float* __restrict__ cls, const float* __restrict__ pe,
                      float* __restrict__ x) {
    int idx = blockIdx.x * 256 + threadIdx.x;
    if (idx >= 128 * 64) return;
    int n = idx >> 6, j = idx & 63;
    x[(size_t)n * 197 * 64 + j] = cls[j] + pe[j];
}

// ---------- LN1 + QKV projection ----------
__global__ __launch_bounds__(256, 2) void k_ln_qkv(
    const float* __restrict__ x, const float* __restrict__ g, const float* __restrict__ bta,
    const float* __restrict__ Wq, const float* __restrict__ bq,
    const float* __restrict__ Wk, const float* __restrict__ bk,
    const float* __restrict__ Wv, const float* __restrict__ bv,
    float* __restrict__ q, float* __restrict__ k, float* __restrict__ v, int S)
{
    __shared__ float z[4][64];
    int tid = threadIdx.x, w = tid >> 6, l = tid & 63;
    int row = blockIdx.x * 4 + w;
    if (row >= N_IMG * S) return;
    float xv = x[(size_t)row * 64 + l];
    float m = wave_sum(xv) * (1.0f / 64.0f);
    float t = xv - m;
    float var = wave_sum(t * t) * (1.0f / 64.0f);
    float zv = t * rsqrtf(var + EPS) * g[l] + bta[l];
    z[w][l] = zv;
    int h = l >> 4, e = l & 15;
    const float* zh = &z[w][h * 16];
    const float* wq = Wq + h * 256 + e;
    const float* wk = Wk + h * 256 + e;
    const float* wv = Wv + h * 256 + e;
    float aq = bq[l], ak = bk[l], av = bv[l];
    #pragma unroll
    for (int d = 0; d < 16; ++d) {
        float zd = zh[d];
        aq += zd * wq[d * 16];
        ak += zd * wk[d * 16];
        av += zd * wv[d * 16];
    }
    int n = row / S, s = row - n * S;
    size_t o = ((size_t)((n * 4 + h) * S + s)) * 16 + e;
    q[o] = aq; k[o] = ak; v[o] = av;
}

// ---------- attention partials: flash-style split-K x4 over key slices ----------
struct KV { float4 k[2][4]; float4 v[2][4]; };

__device__ __forceinline__ void ld_pair(KV& b, const float* kp, const float* vp, int j) {
    #pragma unroll
    for (int u = 0; u < 2; ++u) {
        #pragma unroll
        for (int c = 0; c < 4; ++c) {
            b.k[u][c] = *(const float4*)(kp + (size_t)(j + u) * 16 + c * 4);
            b.v[u][c] = *(const float4*)(vp + (size_t)(j + u) * 16 + c * 4);
        }
    }
}

__device__ __forceinline__ void comp_one(const KV& b, int u, const float4* qv,
                                         float& l, float4* o) {
    float sc = dot4(qv[0], b.k[u][0]) + dot4(qv[1], b.k[u][1]) +
               dot4(qv[2], b.k[u][2]) + dot4(qv[3], b.k[u][3]);
    float p = __expf(sc);
    l += p;
    fma4(o[0], p, b.v[u][0]); fma4(o[1], p, b.v[u][1]);
    fma4(o[2], p, b.v[u][2]); fma4(o[3], p, b.v[u][3]);
}

// grid (512, 4): blockIdx.x = n*4+h, blockIdx.y = key slice (~50 keys).
__global__ __launch_bounds__(256, 8) void k_attn_part(
    const float* __restrict__ q, const float* __restrict__ k, const float* __restrict__ v,
    float* __restrict__ o_part, float* __restrict__ l_part, int S)
{
    int h = blockIdx.x & 3, n = blockIdx.x >> 2;
    int ks = blockIdx.y;
    int per = (S + 3) >> 2;
    int start = ks * per;
    int len = S - start; if (len > per) len = per;
    int tid = threadIdx.x;
    int s = tid < S ? tid : S - 1;
    const float* qrow = q + ((size_t)((n * 4 + h) * S + s)) * 16;
    float4 qv[4];
    #pragma unroll
    for (int c = 0; c < 4; ++c) {
        float4 t = *(const float4*)(qrow + c * 4);
        t.x *= 0.25f; t.y *= 0.25f; t.z *= 0.25f; t.w *= 0.25f;
        qv[c] = t;
    }
    const float* kp = k + ((size_t)(n * 4 + h) * S + start) * 16;
    const float* vp = v + ((size_t)(n * 4 + h) * S + start) * 16;
    float l = 0.0f;
    float4 o[4];
    #pragma unroll
    for (int c = 0; c < 4; ++c) o[c] = make_float4(0.f, 0.f, 0.f, 0.f);

    KV A, B;
    ld_pair(A, kp, vp, 0);
    int j = 0;
    for (; j + 4 <= len; j += 4) {
        ld_pair(B, kp, vp, j + 2);
        comp_one(A, 0, qv, l, o);
        comp_one(A, 1, qv, l, o);
        ld_pair(A, kp, vp, j + 4);
        comp_one(B, 0, qv, l, o);
        comp_one(B, 1, qv, l, o);
    }
    int rem = len - j;
    if (rem > 0) comp_one(A, 0, qv, l, o);
    if (rem > 1) comp_one(A, 1, qv, l, o);
    if (rem > 2) {
        ld_pair(B, kp, vp, j + 2);
        comp_one(B, 0, qv, l, o);
    }

    if (tid < S) {
        size_t qlin = (size_t)(n * 4 + h) * S + tid;
        float* op = o_part + (size_t)ks * OP_STRIDE + qlin * 16;
        #pragma unroll
        for (int c = 0; c < 4; ++c) *(float4*)(op + c * 4) = o[c];
        l_part[(size_t)ks * LP_STRIDE + qlin] = l;
    }
}

// ---------- combine attention partials: hout = x + (sum o_part) / (sum l_part) ----------
__global__ __launch_bounds__(256) void k_attn_comb(
    const float* __restrict__ o_part, const float* __restrict__ l_part,
    const float* __restrict__ x, float* __restrict__ hout, int S)
{
    int idx = blockIdx.x * 256 + threadIdx.x;      // 0 .. 512*S*4-1
    int qlin = idx >> 2, c4 = (idx & 3) << 2;
    int nh = qlin / S, s = qlin - nh * S;
    int n = nh >> 2, h = nh & 3;
    const float* op = o_part + (size_t)qlin * 16 + c4;
    float4 a = *(const float4*)(op);
    float4 b = *(const float4*)(op + OP_STRIDE);
    float4 c = *(const float4*)(op + 2 * (size_t)OP_STRIDE);
    float4 d = *(const float4*)(op + 3 * (size_t)OP_STRIDE);
    float l = l_part[qlin] + l_part[qlin + LP_STRIDE] +
              l_part[qlin + 2 * LP_STRIDE] + l_part[qlin + 3 * LP_STRIDE];
    float rl = 1.0f / l;
    size_t base = ((size_t)(n * S + s)) * 64 + h * 16 + c4;
    float4 xv = *(const float4*)(x + base);
    float4 w;
    w.x = xv.x + (a.x + b.x + c.x + d.x) * rl;
    w.y = xv.y + (a.y + b.y + c.y + d.y) * rl;
    w.z = xv.z + (a.z + b.z + c.z + d.z) * rl;
    w.w = xv.w + (a.w + b.w + c.w + d.w) * rl;
    *(float4*)(hout + base) = w;
}

// ---------- LN2 + GEMM [rows,64]@[64,256] + bias + GELU -> mid ----------
__global__ __launch_bounds__(256, 4) void k_mlp1(
    const float* __restrict__ hbuf, const float* __restrict__ g, const float* __restrict__ bta,
    const float* __restrict__ W1, const float* __restrict__ b1,
    float* __restrict__ mid)
{
    __shared__ float As[64 * 76];
    __shared__ float Bs[64 * 76];
    int tid = threadIdx.x;
    int tx = tid & 15, ty = tid >> 4;
    int m0 = blockIdx.x * 64;
    int nc = blockIdx.y;
    int r = tid >> 2, cpart = (tid & 3) * 16;
    {
        const float* hp = hbuf + ((size_t)(m0 + r)) * 64 + cpart;
        float4 hv[4];
        #pragma unroll
        for (int i = 0; i < 4; ++i) hv[i] = *(const float4*)(hp + i * 4);
        float ps = 0.f;
        #pragma unroll
        for (int i = 0; i < 4; ++i) ps += hv[i].x + hv[i].y + hv[i].z + hv[i].w;
        ps += __shfl_xor(ps, 1); ps += __shfl_xor(ps, 2);
        float mean = ps * (1.0f / 64.0f);
        float vs = 0.f;
        #pragma unroll
        for (int i = 0; i < 4; ++i) {
            float dx = hv[i].x - mean, dy = hv[i].y - mean, dz = hv[i].z - mean, dw = hv[i].w - mean;
            vs += dx * dx + dy * dy + dz * dz + dw * dw;
        }
        vs += __shfl_xor(vs, 1); vs += __shfl_xor(vs, 2);
        float rstd = rsqrtf(vs * (1.0f / 64.0f) + EPS);
        #pragma unroll
        for (int i = 0; i < 4; ++i) {
            float4 gv = *(const float4*)(g + cpart + i * 4);
            float4 bv = *(const float4*)(bta + cpart + i * 4);
            float4 zv;
            zv.x = (hv[i].x - mean) * rstd * gv.x + bv.x;
            zv.y = (hv[i].y - mean) * rstd * gv.y + bv.y;
            zv.z = (hv[i].z - mean) * rstd * gv.z + bv.z;
            zv.w = (hv[i].w - mean) * rstd * gv.w + bv.w;
            *(float4*)&As[r * 76 + cpart + i * 4] = zv;
        }
    }
    const float* wp = W1 + (size_t)r * 256 + nc * 64 + cpart;
    float4 wv4[4];
    #pragma unroll
    for (int i = 0; i < 4; ++i) wv4[i] = *(const float4*)(wp + i * 4);
    __syncthreads();
    #pragma unroll
    for (int i = 0; i < 4; ++i)
        *(float4*)&Bs[r * 76 + cpart + i * 4] = wv4[i];
    __syncthreads();
    float4 acc[4];
    #pragma unroll
    for (int i = 0; i < 4; ++i) acc[i] = make_float4(0.f, 0.f, 0.f, 0.f);
    #pragma unroll 4
    for (int k4 = 0; k4 < 16; ++k4) {
        float4 a[4], b[4];
        #pragma unroll
        for (int i = 0; i < 4; ++i) a[i] = *(float4*)&As[(ty + 16 * i) * 76 + k4 * 4];
        #pragma unroll
        for (int kk = 0; kk < 4; ++kk) b[kk] = *(float4*)&Bs[(k4 * 4 + kk) * 76 + tx * 4];
        #pragma unroll
        for (int i = 0; i < 4; ++i) {
            fma4(acc[i], a[i].x, b[0]);
            fma4(acc[i], a[i].y, b[1]);
            fma4(acc[i], a[i].z, b[2]);
            fma4(acc[i], a[i].w, b[3]);
        }
    }
    int col = nc * 64 + tx * 4;
    float4 b1v = *(const float4*)(b1 + col);
    #pragma unroll
    for (int i = 0; i < 4; ++i) {
        int row = m0 + ty + 16 * i;
        float4 ov;
        ov.x = gelu_f(acc[i].x + b1v.x);
        ov.y = gelu_f(acc[i].y + b1v.y);
        ov.z = gelu_f(acc[i].z + b1v.z);
        ov.w = gelu_f(acc[i].w + b1v.w);
        *(float4*)&mid[(size_t)row * 256 + col] = ov;
    }
}

// ---------- GEMM [rows,256]@[256,64] + bias + residual -> out ----------
__global__ __launch_bounds__(256, 4) void k_mlp2(
    const float* __restrict__ mid, const float* __restrict__ W2, const float* __restrict__ b2,
    const float* __restrict__ hbuf, float* __restrict__ out)
{
    __shared__ float As[32 * 76];
    __shared__ float Bs[64 * 76];
    int tid = threadIdx.x;
    int tx = tid & 15, ty = tid >> 4;
    int m0 = blockIdx.x * 32;
    int ra = tid >> 3, ca = (tid & 7) * 8;
    int rb = tid >> 2, cb = (tid & 3) * 16;
    float4 acc[2];
    acc[0] = make_float4(0.f, 0.f, 0.f, 0.f);
    acc[1] = make_float4(0.f, 0.f, 0.f, 0.f);
    for (int kc = 0; kc < 4; ++kc) {
        const float* mp = mid + ((size_t)(m0 + ra)) * 256 + kc * 64 + ca;
        float4 av0 = *(const float4*)(mp);
        float4 av1 = *(const float4*)(mp + 4);
        const float* wp = W2 + (size_t)(kc * 64 + rb) * 64 + cb;
        float4 wv4[4];
        #pragma unroll
        for (int i = 0; i < 4; ++i) wv4[i] = *(const float4*)(wp + i * 4);
        __syncthreads();
        *(float4*)&As[ra * 76 + ca]     = av0;
        *(float4*)&As[ra * 76 + ca + 4] = av1;
        #pragma unroll
        for (int i = 0; i < 4; ++i)
            *(float4*)&Bs[rb * 76 + cb + i * 4] = wv4[i];
        __syncthreads();
        #pragma unroll 4
        for (int k4 = 0; k4 < 16; ++k4) {
            float4 a[2], b[4];
            a[0] = *(float4*)&As[ty * 76 + k4 * 4];
            a[1] = *(float4*)&As[(ty + 16) * 76 + k4 * 4];
            #pragma unroll
            for (int kk = 0; kk < 4; ++kk) b[kk] = *(float4*)&Bs[(k4 * 4 + kk) * 76 + tx * 4];
            #pragma unroll
            for (int i = 0; i < 2; ++i) {
                fma4(acc[i], a[i].x, b[0]);
                fma4(acc[i], a[i].y, b[1]);
                fma4(acc[i], a[i].z, b[2]);
                fma4(acc[i], a[i].w, b[3]);
            }
        }
    }
    int col = tx * 4;
    float4 b2v = *(const float4*)(b2 + col);
    #pragma unroll
    for (int i = 0; i < 2; ++i) {
        int row = m0 + ty + 16 * i;
        float4 hv = *(const float4*)(hbuf + (size_t)row * 64 + col);
        float4 ov;
        ov.x = acc[i].x + b2v.x + hv.x;
        ov.y = acc[i].y + b2v.y + hv.y;
        ov.z = acc[i].z + b2v.z + hv.z;
        ov.w = acc[i].w + b2v.w + hv.w;
        *(float4*)&out[(size_t)row * 64 + col] = ov;
    }
}

// ---------- bottleneck ----------
__global__ __launch_bounds__(256) void k_bneck(
    const float* __restrict__ xenc, const float* __restrict__ m1W, const float* __restrict__ m1b,
    const float* __restrict__ m4W, const float* __restrict__ m4b,
    float* __restrict__ lat_out, float* __restrict__ xdec)
{
    int tid = threadIdx.x, w = tid >> 6, l = tid & 63;
    int row = blockIdx.x * 4 + w;
    if (row >= 128 * 196) return;
    int n = row / 196, p = row - n * 196;
    float xv = xenc[((size_t)(n * 197 + 1 + p)) * 64 + l];
    float sum = wave_sum(xv * m1W[l]);
    float lat = gelu_f(sum + m1b[0]);
    if (l == 0) lat_out[row] = lat;
    float ov = gelu_f(lat * m4W[l] + m4b[l]);
    xdec[(size_t)row * 64 + l] = ov;
}

// ---------- final: img = depatchify((x + pe196) @ lm2_W + lm2_b) ----------
// BM=64, grid (392,4), 4 col-tiles/block (R4 reuse), but LDS cut to 27136 B via
// As stride 68 + Bs double-chunked [32][76] -> 6 blocks/CU, whole grid co-resident.
__global__ __launch_bounds__(256, 6) void k_final(
    const float* __restrict__ xdec, const float* __restrict__ pe,
    const float* __restrict__ W, const float* __restrict__ bias,
    float* __restrict__ img_out)
{
    __shared__ float As[64 * 68];
    __shared__ float Bs[32 * 76];
    int tid = threadIdx.x;
    int tx = tid & 15, ty = tid >> 4;
    int m0 = blockIdx.x * 64;
    int r = tid >> 2, cpart = (tid & 3) * 16;
    int rb = tid >> 3, cb = (tid & 7) * 8;
    {
        int row = m0 + r;
        int n = row / 196, p = row - n * 196;
        const float* xp = xdec + (size_t)row * 64 + cpart;
        const float* pp = pe + (size_t)p * 64 + cpart;
        #pragma unroll
        for (int i = 0; i < 4; ++i) {
            float4 xv = *(const float4*)(xp + i * 4);
            float4 pv = *(const float4*)(pp + i * 4);
            float4 zv;
            zv.x = xv.x + pv.x; zv.y = xv.y + pv.y; zv.z = xv.z + pv.z; zv.w = xv.w + pv.w;
            *(float4*)&As[r * 68 + cpart + i * 4] = zv;
        }
    }
    for (int t = 0; t < 4; ++t) {
        int nb = blockIdx.y * 4 + t;
        float4 acc[4];
        #pragma unroll
        for (int i = 0; i < 4; ++i) acc[i] = make_float4(0.f, 0.f, 0.f, 0.f);
        for (int c0 = 0; c0 < 2; ++c0) {
            const float* wp = W + (size_t)(c0 * 32 + rb) * 1024 + nb * 64 + cb;
            float4 w0 = *(const float4*)(wp);
            float4 w1 = *(const float4*)(wp + 4);
            __syncthreads();
            *(float4*)&Bs[rb * 76 + cb]     = w0;
            *(float4*)&Bs[rb * 76 + cb + 4] = w1;
            __syncthreads();
            #pragma unroll 4
            for (int k4 = 0; k4 < 8; ++k4) {
                float4 a[4], b[4];
                #pragma unroll
                for (int i = 0; i < 4; ++i)
                    a[i] = *(float4*)&As[(ty + 16 * i) * 68 + (c0 * 8 + k4) * 4];
                #pragma unroll
                for (int kk = 0; kk < 4; ++kk) b[kk] = *(float4*)&Bs[(k4 * 4 + kk) * 76 + tx * 4];
                #pragma unroll
                for (int i = 0; i < 4; ++i) {
                    fma4(acc[i], a[i].x, b[0]);
                    fma4(acc[i], a[i].y, b[1]);
                    fma4(acc[i], a[i].z, b[2]);
                    fma4(acc[i], a[i].w, b[3]);
                }
            }
        }
        int colj = nb * 64 + tx * 4;
        float4 bv = *(const float4*)(bias + colj);
        int rr = colj >> 5, cc = colj & 31;
        #pragma unroll
        for (int i = 0; i < 4; ++i) {
            int row = m0 + ty + 16 * i;
            int n = row / 196, p = row - n * 196;
            int pi = p / 14, pj = p - pi * 14;
            size_t off = (size_t)n * 200704 + (size_t)(pi * 32 + rr) * 448 + pj * 32 + cc;
            float4 ov;
            ov.x = acc[i].x + bv.x;
            ov.y = acc[i].y + bv.y;
            ov.z = acc[i].z + bv.z;
            ov.w = acc[i].w + bv.w;
            *(float4*)&img_out[off] = ov;
        }
    }
}

// ---------- host launch ----------
extern "C" void kernel_launch(void* const* d_in, const int* in_sizes, int n_in,
                              void* d_out, int out_size, void* d_ws, size_t ws_size,
                              hipStream_t stream) {
    const float* images = (const float*)d_in[0];
    const float* cls    = (const float*)d_in[1];
    const float* lm_W   = (const float*)d_in[2];
    const float* lm_b   = (const float*)d_in[3];
    const float* lm2_W  = (const float*)d_in[4];
    const float* lm2_b  = (const float*)d_in[5];
    const float* m1W    = (const float*)d_in[6];
    const float* m1b    = (const float*)d_in[7];
    const float* m4W    = (const float*)d_in[8];
    const float* m4b    = (const float*)d_in[9];

    float* pe   = (float*)d_ws;
    float* xb   = pe + 12608;          // 128*197*64
    float* hb   = xb + 1614848;
    float* qb   = hb + 1614848;        // qb/kb/vb/midb: contiguous, stride PART_STRIDE
    float* kb   = qb + 1614848;
    float* vb   = kb + 1614848;
    float* midb = vb + 1614848;        // 25216*256 — doubles as o_part during attention

    float* lat_out = (float*)d_out;            // 128*196 floats
    float* img_out = (float*)d_out + 25088;    // 128*448*448 floats; head doubles as l_part scratch

    hipLaunchKernelGGL(k_posemb, dim3(50), dim3(256), 0, stream, pe);
    hipLaunchKernelGGL(k_patch, dim3(392, 4), dim3(256), 0, stream, images, lm_W, qb);
    hipLaunchKernelGGL(k_pcomb, dim3(1568), dim3(256), 0, stream, qb, lm_b, pe, xb);
    hipLaunchKernelGGL(k_cls, dim3(32), dim3(256), 0, stream, cls, pe, xb);

    float* cur_x = xb;
    float* cur_h = hb;
    for (int grp = 0; grp < 2; ++grp) {
        int base = 10 + grp * 14;
        const float* ln1_g = (const float*)d_in[base + 0];
        const float* ln1_b = (const float*)d_in[base + 1];
        const float* ln2_g = (const float*)d_in[base + 2];
        const float* ln2_b = (const float*)d_in[base + 3];
        const float* Wq = (const float*)d_in[base + 4];
        const float* Wk = (const float*)d_in[base + 5];
        const float* Wv = (const float*)d_in[base + 6];
        const float* bq = (const float*)d_in[base + 7];
        const float* bk = (const float*)d_in[base + 8];
        const float* bv = (const float*)d_in[base + 9];
        const float* W1 = (const float*)d_in[base + 10];
        const float* b1 = (const float*)d_in[base + 11];
        const float* W2 = (const float*)d_in[base + 12];
        const float* b2 = (const float*)d_in[base + 13];
        int S = (grp == 0) ? 197 : 196;
        int rows = 128 * S;
        for (int i = 0; i < 2; ++i) {
            hipLaunchKernelGGL(k_ln_qkv, dim3(rows / 4), dim3(256), 0, stream,
                cur_x, ln1_g + i * 64, ln1_b + i * 64,
                Wq + i * 1024, bq + i * 64, Wk + i * 1024, bk + i * 64,
                Wv + i * 1024, bv + i * 64, qb, kb, vb, S);
            hipLaunchKernelGGL(k_attn_part, dim3(512, 4), dim3(256), 0, stream,
                qb, kb, vb, midb, img_out, S);
            hipLaunchKernelGGL(k_attn_comb, dim3(8 * S), dim3(256), 0, stream,
                midb, img_out, cur_x, cur_h, S);
            hipLaunchKernelGGL(k_mlp1, dim3(rows / 64, 4), dim3(256), 0, stream,
                cur_h, ln2_g + i * 64, ln2_b + i * 64, W1 + i * 16384, b1 + i * 256, midb);
            hipLaunchKernelGGL(k_mlp2, dim3(rows / 32), dim3(256), 0, stream,
                midb, W2 + i * 16384, b2 + i * 64, cur_h, cur_x);
        }
        if (grp == 0) {
            hipLaunchKernelGGL(k_bneck, dim3(6272), dim3(256), 0, stream,
                cur_x, m1W, m1b, m4W, m4b, lat_out, hb);
            cur_x = hb;
            cur_h = xb;
        }
    }
    hipLaunchKernelGGL(k_final, dim3(392, 4), dim3(256), 0, stream, cur_x, pe, lm2_W, lm2_b, img_out);
}